// Round 1
// baseline (202048.157 us; speedup 1.0000x reference)
//
#include <hip/hip_runtime.h>
#include <cstdint>
#include <cstddef>

// KNN regressor: out[q] = mean of y_train over the 32 nearest train points.
// score[n] = t_sq[n] - 2*dot(q, x_n)   (q_sq constant per query -> irrelevant to top-k)
//
// Pipeline:
//   1) tsq_kernel : t_sq[n] for n<N, +INF for padded n in [N, NPAD)
//   2) knn_main   : fused fp32 tiled GEMM + threshold-filtered exact top-32 per
//                   (query, N-chunk); writes packed (score|y) u64 candidates to ws
//   3) merge_kernel: per-query top-32 across 8 chunks, mean of y
//
// ws usage: NPAD*4 bytes (tsq) + 4096*8*32*8 bytes (candidates) ~ 8.8 MB.

constexpr int Q_  = 4096;
constexpr int N_  = 100000;
constexpr int D_  = 128;
constexpr int K_  = 32;

constexpr int QT    = 32;              // queries per block
constexpr int BN    = 64;              // train points per tile
constexpr int BK    = 64;              // k-chunk (2 chunks cover D=128)
constexpr int NCH   = 8;               // N chunks (grid.y)
constexpr int CHUNK = 12544;           // 196*64 ; NCH*CHUNK = 100352 >= N_
constexpr int TILES = CHUNK / BN;      // 196
constexpr int NPAD  = NCH * CHUNK;     // 100352
constexpr int CAP   = 160;             // candidate buffer capacity per query
constexpr int TRIG  = 96;              // compact when count > TRIG (CAP-TRIG=BN: no overflow)

#define DEV __device__ __forceinline__

DEV unsigned long long pack_cand(float score, float yv) {
    unsigned int s = __float_as_uint(score);
    s = (s & 0x80000000u) ? ~s : (s | 0x80000000u);   // monotone u32 key
    return ((unsigned long long)s << 32) | (unsigned long long)__float_as_uint(yv);
}
DEV float unpack_score(unsigned long long k) {
    unsigned int s = (unsigned int)(k >> 32);
    s = (s & 0x80000000u) ? (s ^ 0x80000000u) : ~s;
    return __uint_as_float(s);
}
DEV float unpack_y(unsigned long long k) {
    return __uint_as_float((unsigned int)(k & 0xffffffffu));
}
DEV unsigned long long u64min(unsigned long long a, unsigned long long b) {
    return a < b ? a : b;
}

// ---------------------------------------------------------------- t_sq ------
__global__ void tsq_kernel(const float* __restrict__ X, float* __restrict__ tsq) {
    int tid = threadIdx.x;
    int r = blockIdx.x * 16 + (tid >> 4);   // 16 rows/block, 16 lanes/row
    int c = (tid & 15) * 8;
    float s = 0.f;
    if (r < N_) {
        const float4* p = (const float4*)(X + (size_t)r * D_ + c);
        float4 a = p[0], b = p[1];
        s = a.x*a.x + a.y*a.y + a.z*a.z + a.w*a.w
          + b.x*b.x + b.y*b.y + b.z*b.z + b.w*b.w;
    }
    s += __shfl_xor(s, 8);
    s += __shfl_xor(s, 4);
    s += __shfl_xor(s, 2);
    s += __shfl_xor(s, 1);
    if ((tid & 15) == 0 && r < NPAD)
        tsq[r] = (r < N_) ? s : __int_as_float(0x7f800000);   // +INF pad
}

// ------------------------------------------------------------- main ---------
__global__ __launch_bounds__(256, 2) void knn_main(
    const float* __restrict__ Qm, const float* __restrict__ X,
    const float* __restrict__ Ytr, const float* __restrict__ tsq,
    unsigned long long* __restrict__ candOut)
{
    __shared__ float Qt[D_][QT];                    // 16 KB, [d][q]
    __shared__ float Xt[BK][BN];                    // 16 KB, [d][n]
    __shared__ unsigned long long cand[QT][CAP];    // 40 KB packed (key|y)
    __shared__ int   cnt[QT];
    __shared__ float thr[QT];

    const int tid  = threadIdx.x;
    const int lane = tid & 63;
    const int wv   = tid >> 6;
    const int qbase     = blockIdx.x * QT;
    const int chunkBase = blockIdx.y * CHUNK;

    if (tid < QT) { cnt[tid] = 0; thr[tid] = __int_as_float(0x7f800000); }

    // stage Q tile transposed (once per block): 8 threads/row, 16 cols each
    {
        int r  = tid >> 3;
        int c0 = (tid & 7) * 16;
        const float* src = Qm + (size_t)(qbase + r) * D_ + c0;
        #pragma unroll
        for (int l = 0; l < 4; ++l) {
            float4 v = *(const float4*)(src + 4 * l);
            Qt[c0 + 4*l + 0][r] = v.x;
            Qt[c0 + 4*l + 1][r] = v.y;
            Qt[c0 + 4*l + 2][r] = v.z;
            Qt[c0 + 4*l + 3][r] = v.w;
        }
    }

    const int q0 = (tid >> 5) * 4;   // 4 query rows per thread
    const int n0 = (tid & 31) * 2;   // 2 point cols per thread

    for (int t = 0; t < TILES; ++t) {
        const int nb = chunkBase + t * BN;
        float acc[4][2] = {};
        #pragma unroll
        for (int kc = 0; kc < 2; ++kc) {
            __syncthreads();   // Xt free to overwrite; also orders prior compaction
            {
                int r  = tid >> 2;            // 0..63: one train row per 4 threads
                int c0 = (tid & 3) * 16;
                int n  = nb + r;
                const float* src = X + (size_t)n * D_ + kc * BK + c0;
                #pragma unroll
                for (int l = 0; l < 4; ++l) {
                    float4 v = (n < N_) ? *(const float4*)(src + 4 * l)
                                        : float4{0.f, 0.f, 0.f, 0.f};
                    Xt[c0 + 4*l + 0][r] = v.x;
                    Xt[c0 + 4*l + 1][r] = v.y;
                    Xt[c0 + 4*l + 2][r] = v.z;
                    Xt[c0 + 4*l + 3][r] = v.w;
                }
            }
            __syncthreads();
            const int kb = kc * BK;
            #pragma unroll
            for (int kk = 0; kk < BK; ++kk) {
                float4 qv = *(const float4*)&Qt[kb + kk][q0];
                float2 xv = *(const float2*)&Xt[kk][n0];
                acc[0][0] += qv.x * xv.x;  acc[0][1] += qv.x * xv.y;
                acc[1][0] += qv.y * xv.x;  acc[1][1] += qv.y * xv.y;
                acc[2][0] += qv.z * xv.x;  acc[2][1] += qv.z * xv.y;
                acc[3][0] += qv.w * xv.x;  acc[3][1] += qv.w * xv.y;
            }
        }

        // threshold filter + append (rare path after warmup)
        float th[4] = { thr[q0], thr[q0+1], thr[q0+2], thr[q0+3] };
        float ts[2] = { tsq[nb + n0], tsq[nb + n0 + 1] };   // +INF for padded n
        #pragma unroll
        for (int i = 0; i < 4; ++i) {
            #pragma unroll
            for (int j = 0; j < 2; ++j) {
                float s = ts[j] - 2.f * acc[i][j];
                if (s < th[i]) {                 // never true for padded n (INF < INF)
                    int pos = atomicAdd(&cnt[q0 + i], 1);   // pos < CAP by construction
                    float yv = Ytr[nb + n0 + j];
                    cand[q0 + i][pos] = pack_cand(s, yv);
                }
            }
        }
        __syncthreads();

        // wave-parallel compaction: wave w owns queries [w*8, w*8+8)
        const bool lastTile = (t == TILES - 1);
        #pragma unroll 1
        for (int qq = wv * 8; qq < wv * 8 + 8; ++qq) {
            int c = cnt[qq];                       // wave-uniform
            if (c > TRIG || lastTile) {
                unsigned long long r0 = (lane < c)       ? cand[qq][lane]       : ~0ull;
                unsigned long long r1 = (lane + 64 < c)  ? cand[qq][lane + 64]  : ~0ull;
                unsigned long long r2 = (lane + 128 < c) ? cand[qq][lane + 128] : ~0ull;
                unsigned long long kept = ~0ull;
                #pragma unroll 1
                for (int i = 0; i < K_; ++i) {
                    unsigned long long g = u64min(r0, u64min(r1, r2));
                    g = u64min(g, __shfl_xor(g, 32));
                    g = u64min(g, __shfl_xor(g, 16));
                    g = u64min(g, __shfl_xor(g, 8));
                    g = u64min(g, __shfl_xor(g, 4));
                    g = u64min(g, __shfl_xor(g, 2));
                    g = u64min(g, __shfl_xor(g, 1));
                    if (lane == i) kept = g;
                    bool has = (r0 == g) || (r1 == g) || (r2 == g);
                    unsigned long long bal = __ballot(has);
                    int fl = __ffsll(bal) - 1;     // clear exactly one instance
                    if (lane == fl) {
                        if (r0 == g) r0 = ~0ull;
                        else if (r1 == g) r1 = ~0ull;
                        else r2 = ~0ull;
                    }
                }
                if (lastTile) {
                    if (lane < K_)
                        candOut[((size_t)(qbase + qq) * NCH + blockIdx.y) * K_ + lane] = kept;
                } else {
                    if (lane < K_) cand[qq][lane] = kept;
                    if (lane == K_ - 1) thr[qq] = unpack_score(kept);  // 32nd smallest
                    if (lane == 0) cnt[qq] = K_;
                }
            }
        }
        // next iteration's first __syncthreads() orders this phase
    }
}

// ------------------------------------------------------------- merge --------
__global__ void merge_kernel(const unsigned long long* __restrict__ candIn,
                             float* __restrict__ out)
{
    int tid  = threadIdx.x;
    int lane = tid & 63;
    int wv   = tid >> 6;
    int q    = blockIdx.x * 4 + wv;                 // one wave per query
    const unsigned long long* p = candIn + (size_t)q * (NCH * K_);  // 256 cands
    unsigned long long r0 = p[lane];
    unsigned long long r1 = p[lane + 64];
    unsigned long long r2 = p[lane + 128];
    unsigned long long r3 = p[lane + 192];
    float sum = 0.f;
    #pragma unroll 1
    for (int i = 0; i < K_; ++i) {
        unsigned long long g = u64min(u64min(r0, r1), u64min(r2, r3));
        g = u64min(g, __shfl_xor(g, 32));
        g = u64min(g, __shfl_xor(g, 16));
        g = u64min(g, __shfl_xor(g, 8));
        g = u64min(g, __shfl_xor(g, 4));
        g = u64min(g, __shfl_xor(g, 2));
        g = u64min(g, __shfl_xor(g, 1));
        bool has = (r0 == g) || (r1 == g) || (r2 == g) || (r3 == g);
        unsigned long long bal = __ballot(has);
        int fl = __ffsll(bal) - 1;
        if (lane == fl) {
            if (r0 == g) r0 = ~0ull;
            else if (r1 == g) r1 = ~0ull;
            else if (r2 == g) r2 = ~0ull;
            else r3 = ~0ull;
        }
        sum += unpack_y(g);
    }
    if (lane == 0) out[q] = sum * (1.f / K_);
}

// ------------------------------------------------------------- launch -------
extern "C" void kernel_launch(void* const* d_in, const int* in_sizes, int n_in,
                              void* d_out, int out_size, void* d_ws, size_t ws_size,
                              hipStream_t stream)
{
    const float* Qm  = (const float*)d_in[0];   // [4096,128]
    const float* X   = (const float*)d_in[1];   // [100000,128]
    const float* Ytr = (const float*)d_in[2];   // [100000]
    float* out = (float*)d_out;                 // [4096]

    float* tsq = (float*)d_ws;                                    // NPAD floats
    size_t candOff = ((size_t)NPAD * sizeof(float) + 255) & ~(size_t)255;
    unsigned long long* cand = (unsigned long long*)((char*)d_ws + candOff);
    // total ws: 401664 + 4096*8*32*8 = ~8.8 MB

    tsq_kernel<<<NPAD / 16, 256, 0, stream>>>(X, tsq);
    dim3 grid(Q_ / QT, NCH);
    knn_main<<<grid, 256, 0, stream>>>(Qm, X, Ytr, tsq, cand);
    merge_kernel<<<Q_ / 4, 256, 0, stream>>>(cand, out);
}

// Round 2
// 1608.199 us; speedup vs baseline: 125.6363x; 125.6363x over previous
//
#include <hip/hip_runtime.h>
#include <hip/hip_fp16.h>
#include <cstdint>
#include <cstddef>

// KNN regressor, MFMA edition.
//   score[n] = tsq[n] - 2*dot(q, x_n)   (q_sq const per query -> top-k invariant)
// dot computed via fp16 split: x = h + r, h = fp16(x), r = fp16(x - h).
// 3 MFMA passes (hh, hr, rh) give ~fp32 accuracy (dropped r*r ~ 2e-7).
// Selection: per-(query,chunk) approx top-32 -> merge 8 chunks -> approx top-40
// -> EXACT fp32 rescore -> exact top-32 -> mean(y).
//
// MFMA 16x16x32 f16, HW-verified layouts (learn_hip m89/m91/m120):
//   A[m][k]: m = lane&15, k = (lane>>4)*8 + j   (j=0..7, contiguous k -> b128)
//   B[k][n]: n = lane&15, k = (lane>>4)*8 + j
//   C[m][n]: n(col) = lane&15, m(row) = (lane>>4)*4 + reg

constexpr int Q_  = 4096;
constexpr int N_  = 100000;
constexpr int D_  = 128;
constexpr int K_  = 32;

constexpr int QT    = 32;            // queries per block
constexpr int BN    = 256;           // n per outer iteration
constexpr int NCH   = 8;             // chunks (grid.y)
constexpr int CHUNK = 12544;         // 49*256
constexpr int ITERS = CHUNK / BN;    // 49
constexpr int NPAD  = NCH * CHUNK;   // 100352
constexpr int CCAP  = 64;            // per-query candidate buffer (LDS)
constexpr int MKEEP = 40;            // merge keeps approx-top-40 for exact rescore

typedef __attribute__((ext_vector_type(8))) _Float16 half8;
typedef __attribute__((ext_vector_type(4))) float    floatx4;
typedef unsigned long long ull;

#define DEV __device__ __forceinline__

DEV ull pack_cand(float score, unsigned int n) {
    unsigned int s = __float_as_uint(score);
    s = (s & 0x80000000u) ? ~s : (s | 0x80000000u);   // monotone u32 key
    return ((ull)s << 32) | (ull)n;
}
DEV float unpack_score(ull k) {
    unsigned int s = (unsigned int)(k >> 32);
    s = (s & 0x80000000u) ? (s ^ 0x80000000u) : ~s;
    return __uint_as_float(s);
}
DEV ull u64min(ull a, ull b) { return a < b ? a : b; }
DEV float inf_f() { return __int_as_float(0x7f800000); }

// ---------------------------------------------------------------- prep ------
// One wave per row: lane holds cols {2L, 2L+1}. Writes fp16 hi/res splits.
__global__ void prep_x(const float* __restrict__ X, __half* __restrict__ Xh,
                       __half* __restrict__ Xr, float* __restrict__ tsq) {
    int L = threadIdx.x & 63;
    int r = blockIdx.x * 4 + (threadIdx.x >> 6);     // r < NPAD by grid
    float2 x = {0.f, 0.f};
    if (r < N_) x = *(const float2*)(X + (size_t)r * D_ + 2 * L);
    __half h0 = __float2half(x.x), h1 = __float2half(x.y);
    __half r0 = __float2half(x.x - __half2float(h0));
    __half r1 = __float2half(x.y - __half2float(h1));
    size_t o = (size_t)r * D_ + 2 * L;
    Xh[o] = h0; Xh[o + 1] = h1;
    Xr[o] = r0; Xr[o + 1] = r1;
    float s = x.x * x.x + x.y * x.y;
    s += __shfl_xor(s, 32); s += __shfl_xor(s, 16); s += __shfl_xor(s, 8);
    s += __shfl_xor(s, 4);  s += __shfl_xor(s, 2);  s += __shfl_xor(s, 1);
    if (L == 0) tsq[r] = (r < N_) ? s : inf_f();
}

__global__ void prep_q(const float* __restrict__ Qm, __half* __restrict__ Qh,
                       __half* __restrict__ Qr) {
    int L = threadIdx.x & 63;
    int r = blockIdx.x * 4 + (threadIdx.x >> 6);     // r < 4096 by grid
    float2 x = *(const float2*)(Qm + (size_t)r * D_ + 2 * L);
    __half h0 = __float2half(x.x), h1 = __float2half(x.y);
    size_t o = (size_t)r * D_ + 2 * L;
    Qh[o] = h0; Qh[o + 1] = h1;
    Qr[o] = __float2half(x.x - __half2float(h0));
    Qr[o + 1] = __float2half(x.y - __half2float(h1));
}

// ------------------------------------------------------------- main ---------
__global__ __launch_bounds__(256, 2) void knn_main(
    const __half* __restrict__ Qh, const __half* __restrict__ Qr,
    const __half* __restrict__ Xh, const __half* __restrict__ Xr,
    const float* __restrict__ tsq, ull* __restrict__ candOut)
{
    // B tiles (Bh,Br: [256 n][32 k] fp16, k contiguous) union'd with the
    // fp32 score matrix [32 q][256 n] -- both 32 KB, used in disjoint phases.
    __shared__ __align__(16) char bsc[32768];
    __half* Bh = (__half*)bsc;
    __half* Br = (__half*)(bsc + 16384);
    float*  sc = (float*)bsc;
    __shared__ __align__(16) float tsqT[BN];
    __shared__ ull   cand[QT][CCAP];                  // 16 KB (score|n) packed
    __shared__ float thrL[QT];
    __shared__ int   cntL[QT];

    const int tid = threadIdx.x;
    const int L   = tid & 63;
    const int wv  = tid >> 6;
    const int qbase = blockIdx.x * QT;
    const int ch    = blockIdx.y;
    const int chBase = ch * CHUNK;
    const int nwv = wv * 64;                          // wave's 64-col n window

    if (tid < QT) { cntL[tid] = 0; thrL[tid] = inf_f(); }

    // A fragments in registers: [qt][ks], all-constant indexing (no scratch).
    const int am = L & 15, aq = L >> 4;
    half8 afh[2][4], afr[2][4];
    #pragma unroll
    for (int qt = 0; qt < 2; ++qt)
        #pragma unroll
        for (int ks = 0; ks < 4; ++ks) {
            size_t o = (size_t)(qbase + qt * 16 + am) * D_ + ks * 32 + aq * 8;
            afh[qt][ks] = *(const half8*)(Qh + o);
            afr[qt][ks] = *(const half8*)(Qr + o);
        }

    #pragma unroll 1
    for (int it = 0; it < ITERS; ++it) {
        const int nbase = chBase + it * BN;
        floatx4 acc[2][4] = {};

        #pragma unroll
        for (int ks = 0; ks < 4; ++ks) {
            __syncthreads();   // B free (prev mfma / prev filter done)
            {   // stage Bh/Br[256][32] for k-window [ks*32, ks*32+32)
                int koff = (tid & 3) * 8;             // 8 halves = 16 B
                #pragma unroll
                for (int rep = 0; rep < 4; ++rep) {
                    int row = rep * 64 + (tid >> 2);
                    size_t o = (size_t)(nbase + row) * D_ + ks * 32 + koff;
                    *(half8*)(Bh + row * 32 + koff) = *(const half8*)(Xh + o);
                    *(half8*)(Br + row * 32 + koff) = *(const half8*)(Xr + o);
                }
                if (ks == 0) tsqT[tid] = tsq[nbase + tid];
            }
            __syncthreads();
            #pragma unroll
            for (int nt = 0; nt < 4; ++nt) {
                const __half* bp = Bh + (nwv + nt * 16 + am) * 32 + aq * 8;
                const __half* rp = Br + (nwv + nt * 16 + am) * 32 + aq * 8;
                half8 bh = *(const half8*)bp;
                half8 br = *(const half8*)rp;
                #pragma unroll
                for (int qt = 0; qt < 2; ++qt) {
                    acc[qt][nt] = __builtin_amdgcn_mfma_f32_16x16x32_f16(
                        afh[qt][ks], bh, acc[qt][nt], 0, 0, 0);   // hh
                    acc[qt][nt] = __builtin_amdgcn_mfma_f32_16x16x32_f16(
                        afh[qt][ks], br, acc[qt][nt], 0, 0, 0);   // hr
                    acc[qt][nt] = __builtin_amdgcn_mfma_f32_16x16x32_f16(
                        afr[qt][ks], bh, acc[qt][nt], 0, 0, 0);   // rh
                }
            }
        }
        __syncthreads();       // all mfma reads done -> reuse B space as scores
        #pragma unroll
        for (int qt = 0; qt < 2; ++qt)
            #pragma unroll
            for (int nt = 0; nt < 4; ++nt)
                #pragma unroll
                for (int rg = 0; rg < 4; ++rg) {
                    int q = qt * 16 + aq * 4 + rg;            // C row = query
                    int n = nwv + nt * 16 + am;               // C col = point
                    sc[q * 256 + n] = acc[qt][nt][rg];
                }
        __syncthreads();

        // Wave-private filter: wave wv owns queries [8wv, 8wv+8), all 256 n.
        #pragma unroll 1
        for (int q8 = 0; q8 < 8; ++q8) {
            const int q = wv * 8 + q8;
            int   cnt_c = cntL[q];
            float thr_c = thrL[q];
            float4 d  = *(const float4*)(sc + q * 256 + 4 * L);
            float4 t4 = *(const float4*)(tsqT + 4 * L);
            float s0 = t4.x - 2.f * d.x, s1 = t4.y - 2.f * d.y;
            float s2 = t4.z - 2.f * d.z, s3 = t4.w - 2.f * d.w;
            bool anyw = (s0 < thr_c) | (s1 < thr_c) | (s2 < thr_c) | (s3 < thr_c);
            if (__ballot(anyw)) {
                #pragma unroll
                for (int j = 0; j < 4; ++j) {
                    float sj = (j == 0) ? s0 : (j == 1) ? s1 : (j == 2) ? s2 : s3;
                    unsigned int ng = (unsigned int)(nbase + 4 * L + j);
                    bool want = sj < thr_c;
                    while (__ballot(want)) {
                        ull wm = __ballot(want);
                        int pos = cnt_c + __popcll(wm & ((1ull << L) - 1ull));
                        if (want && pos < CCAP) {
                            cand[q][pos] = pack_cand(sj, ng);
                            want = false;
                        }
                        int added = (int)__popcll(wm);
                        cnt_c = (cnt_c + added > CCAP) ? CCAP : cnt_c + added;
                        if (__ballot(want)) {     // overflow -> wave compact
                            ull v = (L < cnt_c) ? cand[q][L] : ~0ull;
                            #pragma unroll
                            for (int k = 2; k <= 64; k <<= 1)
                                #pragma unroll
                                for (int jj = k >> 1; jj >= 1; jj >>= 1) {
                                    ull o = __shfl_xor(v, jj);
                                    bool up = ((L & k) == 0);
                                    bool lo = ((L & jj) == 0);
                                    ull mn = u64min(v, o), mx = v ^ o ^ mn;
                                    v = (lo == up) ? mn : mx;
                                }
                            if (L < K_) cand[q][L] = v;
                            cnt_c = K_;
                            thr_c = unpack_score(__shfl(v, K_ - 1));
                            want = want && (sj < thr_c);
                        }
                    }
                }
            }
            cntL[q] = cnt_c;
            thrL[q] = thr_c;
        }
        // next iter's first __syncthreads() orders sc/cand phases
    }

    // final: sort each owned query's buffer, emit sorted approx top-32
    #pragma unroll 1
    for (int q8 = 0; q8 < 8; ++q8) {
        const int q = wv * 8 + q8;
        int m = cntL[q]; if (m > CCAP) m = CCAP;
        ull v = (L < m) ? cand[q][L] : ~0ull;
        #pragma unroll
        for (int k = 2; k <= 64; k <<= 1)
            #pragma unroll
            for (int jj = k >> 1; jj >= 1; jj >>= 1) {
                ull o = __shfl_xor(v, jj);
                bool up = ((L & k) == 0);
                bool lo = ((L & jj) == 0);
                ull mn = u64min(v, o), mx = v ^ o ^ mn;
                v = (lo == up) ? mn : mx;
            }
        if (L < K_)
            candOut[((size_t)(qbase + q) * NCH + ch) * K_ + L] = v;
    }
}

// ---------------------------------------------------- merge + exact rescore -
__global__ void merge_rescore(const ull* __restrict__ candIn,
                              const float* __restrict__ Qm,
                              const float* __restrict__ X,
                              const float* __restrict__ tsq,
                              const float* __restrict__ Ytr,
                              float* __restrict__ out)
{
    int L  = threadIdx.x & 63;
    int q  = blockIdx.x * 4 + (threadIdx.x >> 6);   // one wave per query
    const ull* p = candIn + (size_t)q * (NCH * K_); // 256 approx candidates
    ull r0 = p[L], r1 = p[L + 64], r2 = p[L + 128], r3 = p[L + 192];

    // approx top-MKEEP; lane i captures the i-th best
    ull sel = ~0ull;
    #pragma unroll 1
    for (int i = 0; i < MKEEP; ++i) {
        ull g = u64min(u64min(r0, r1), u64min(r2, r3));
        g = u64min(g, __shfl_xor(g, 32)); g = u64min(g, __shfl_xor(g, 16));
        g = u64min(g, __shfl_xor(g, 8));  g = u64min(g, __shfl_xor(g, 4));
        g = u64min(g, __shfl_xor(g, 2));  g = u64min(g, __shfl_xor(g, 1));
        if (L == i) sel = g;
        bool has = (r0 == g) | (r1 == g) | (r2 == g) | (r3 == g);
        int fl = __ffsll(__ballot(has)) - 1;
        if (L == fl) {
            if (r0 == g) r0 = ~0ull; else if (r1 == g) r1 = ~0ull;
            else if (r2 == g) r2 = ~0ull; else r3 = ~0ull;
        }
    }

    // exact fp32 rescore of the MKEEP candidates (wave-cooperative dot)
    float2 qv = *(const float2*)(Qm + (size_t)q * D_ + 2 * L);
    ull key = ~0ull;
    #pragma unroll 1
    for (int c = 0; c < MKEEP; ++c) {
        ull s = __shfl(sel, c);
        unsigned int n = (unsigned int)(s & 0xffffffffu);
        float2 xv = *(const float2*)(X + (size_t)n * D_ + 2 * L);
        float pd = qv.x * xv.x + qv.y * xv.y;
        pd += __shfl_xor(pd, 32); pd += __shfl_xor(pd, 16);
        pd += __shfl_xor(pd, 8);  pd += __shfl_xor(pd, 4);
        pd += __shfl_xor(pd, 2);  pd += __shfl_xor(pd, 1);
        float scv = tsq[n] - 2.f * pd;
        if (L == c) key = pack_cand(scv, n);
    }

    // exact top-32 of MKEEP, mean of y
    ull kv = key;
    bool kept = false;
    #pragma unroll 1
    for (int i = 0; i < K_; ++i) {
        ull g = kv;
        g = u64min(g, __shfl_xor(g, 32)); g = u64min(g, __shfl_xor(g, 16));
        g = u64min(g, __shfl_xor(g, 8));  g = u64min(g, __shfl_xor(g, 4));
        g = u64min(g, __shfl_xor(g, 2));  g = u64min(g, __shfl_xor(g, 1));
        int fl = __ffsll(__ballot(kv == g)) - 1;
        if (L == fl) { kv = ~0ull; kept = true; }
    }
    float ys = kept ? Ytr[(unsigned int)(key & 0xffffffffu)] : 0.f;
    ys += __shfl_xor(ys, 32); ys += __shfl_xor(ys, 16); ys += __shfl_xor(ys, 8);
    ys += __shfl_xor(ys, 4);  ys += __shfl_xor(ys, 2);  ys += __shfl_xor(ys, 1);
    if (L == 0) out[q] = ys * (1.f / K_);
}

// ------------------------------------------------------------- launch -------
extern "C" void kernel_launch(void* const* d_in, const int* in_sizes, int n_in,
                              void* d_out, int out_size, void* d_ws, size_t ws_size,
                              hipStream_t stream)
{
    const float* Qm  = (const float*)d_in[0];   // [4096,128]
    const float* X   = (const float*)d_in[1];   // [100000,128]
    const float* Ytr = (const float*)d_in[2];   // [100000]
    float* out = (float*)d_out;                 // [4096]

    char* w = (char*)d_ws;
    __half* Xh = (__half*)w;                         w += (size_t)NPAD * D_ * 2;  // 25.7 MB
    __half* Xr = (__half*)w;                         w += (size_t)NPAD * D_ * 2;  // 25.7 MB
    __half* Qh = (__half*)w;                         w += (size_t)Q_ * D_ * 2;    // 1 MB
    __half* Qr = (__half*)w;                         w += (size_t)Q_ * D_ * 2;    // 1 MB
    float*  ts = (float*)w;                          w += (size_t)NPAD * 4;       // 0.4 MB
    ull*    cd = (ull*)w;                            // 8.4 MB  (total ~62.3 MB)

    prep_x<<<NPAD / 4, 256, 0, stream>>>(X, Xh, Xr, ts);
    prep_q<<<Q_ / 4, 256, 0, stream>>>(Qm, Qh, Qr);
    dim3 grid(Q_ / QT, NCH);
    knn_main<<<grid, 256, 0, stream>>>(Qh, Qr, Xh, Xr, ts, cd);
    merge_rescore<<<Q_ / 4, 256, 0, stream>>>(cd, Qm, X, ts, Ytr, out);
}

// Round 3
// 1166.005 us; speedup vs baseline: 173.2824x; 1.3792x over previous
//
#include <hip/hip_runtime.h>
#include <hip/hip_fp16.h>
#include <cstdint>
#include <cstddef>

// KNN regressor, MFMA edition v3.
//   score[n] = tsq[n] - 2*dot(q, x_n)
// dot via 2-pass fp16 split: q = qh + qr (fp16 hi + fp16 residual), x ~ xh.
//   dot ≈ qh·xh + qr·xh  (both passes share the same B fragment -> Xr dropped)
// Dropped term qh·xr ~ 7e-3 absolute; selection keeps per-chunk approx top-32,
// merge keeps approx top-40, then EXACT fp32 rescore -> exact top-32 -> mean.
//
// Staging via __builtin_amdgcn_global_load_lds width=16 (dest = base+lane*16).
// XCD-affinity: chunk = blockIdx.x & 7 so each XCD L2 caches one 3.2 MB chunk.
//
// MFMA 16x16x32 f16, HW-verified layouts (learn_hip m89/m91/m120):
//   A[m][k]: m = lane&15, k = (lane>>4)*8 + j
//   B[k][n]: n = lane&15, k = (lane>>4)*8 + j
//   C[m][n]: n(col) = lane&15, m(row) = (lane>>4)*4 + reg

constexpr int Q_  = 4096;
constexpr int N_  = 100000;
constexpr int D_  = 128;
constexpr int K_  = 32;

constexpr int QT    = 32;            // queries per block
constexpr int BN    = 256;           // n per outer iteration
constexpr int NCH   = 8;             // chunks (grid: ch = blockIdx.x & 7)
constexpr int CHUNK = 12544;         // 49*256
constexpr int ITERS = CHUNK / BN;    // 49
constexpr int NPAD  = NCH * CHUNK;   // 100352
constexpr int CCAP  = 64;            // per-query candidate buffer (LDS)
constexpr int MKEEP = 40;            // merge keeps approx-top-40 for exact rescore
constexpr int SCS   = 268;           // sc row stride in floats (2-way banks, 16B-aligned)

typedef __attribute__((ext_vector_type(8))) _Float16 half8;
typedef __attribute__((ext_vector_type(4))) float    floatx4;
typedef unsigned long long ull;

#define DEV __device__ __forceinline__

#define GLD16(gp, lp) __builtin_amdgcn_global_load_lds( \
    (const __attribute__((address_space(1))) void*)(gp), \
    (__attribute__((address_space(3))) void*)(lp), 16, 0, 0)
#define GLD4(gp, lp) __builtin_amdgcn_global_load_lds( \
    (const __attribute__((address_space(1))) void*)(gp), \
    (__attribute__((address_space(3))) void*)(lp), 4, 0, 0)

DEV ull pack_cand(float score, unsigned int n) {
    unsigned int s = __float_as_uint(score);
    s = (s & 0x80000000u) ? ~s : (s | 0x80000000u);   // monotone u32 key
    return ((ull)s << 32) | (ull)n;
}
DEV float unpack_score(ull k) {
    unsigned int s = (unsigned int)(k >> 32);
    s = (s & 0x80000000u) ? (s ^ 0x80000000u) : ~s;
    return __uint_as_float(s);
}
DEV ull u64min(ull a, ull b) { return a < b ? a : b; }
DEV float inf_f() { return __int_as_float(0x7f800000); }

// ---------------------------------------------------------------- prep ------
// One wave per row: lane holds cols {2L, 2L+1}. fp16 hi split + row sumsq.
__global__ void prep_x(const float* __restrict__ X, __half* __restrict__ Xh,
                       float* __restrict__ tsq) {
    int L = threadIdx.x & 63;
    int r = blockIdx.x * 4 + (threadIdx.x >> 6);     // r < NPAD by grid
    float2 x = {0.f, 0.f};
    if (r < N_) x = *(const float2*)(X + (size_t)r * D_ + 2 * L);
    size_t o = (size_t)r * D_ + 2 * L;
    Xh[o]     = __float2half(x.x);
    Xh[o + 1] = __float2half(x.y);
    float s = x.x * x.x + x.y * x.y;
    s += __shfl_xor(s, 32); s += __shfl_xor(s, 16); s += __shfl_xor(s, 8);
    s += __shfl_xor(s, 4);  s += __shfl_xor(s, 2);  s += __shfl_xor(s, 1);
    if (L == 0) tsq[r] = (r < N_) ? s : inf_f();
}

__global__ void prep_q(const float* __restrict__ Qm, __half* __restrict__ Qh,
                       __half* __restrict__ Qr) {
    int L = threadIdx.x & 63;
    int r = blockIdx.x * 4 + (threadIdx.x >> 6);     // r < 4096 by grid
    float2 x = *(const float2*)(Qm + (size_t)r * D_ + 2 * L);
    __half h0 = __float2half(x.x), h1 = __float2half(x.y);
    size_t o = (size_t)r * D_ + 2 * L;
    Qh[o] = h0; Qh[o + 1] = h1;
    Qr[o]     = __float2half(x.x - __half2float(h0));
    Qr[o + 1] = __float2half(x.y - __half2float(h1));
}

// ------------------------------------------------------------- main ---------
__global__ __launch_bounds__(256, 3) void knn_main(
    const __half* __restrict__ Qh, const __half* __restrict__ Qr,
    const __half* __restrict__ Xh, const float* __restrict__ tsq,
    ull* __restrict__ candOut)
{
    // B tile (Bh: [256 n][32 k] fp16) union'd with the fp32 score matrix
    // sc[32 q][SCS] -- disjoint phases. 34304 B total.
    __shared__ __align__(16) char bsc[QT * SCS * 4];
    __half* Bh = (__half*)bsc;
    float*  sc = (float*)bsc;
    __shared__ __align__(16) float tsqT[BN];
    __shared__ ull   cand[QT][CCAP];                  // 16 KB (score|n)
    __shared__ float thrL[QT];
    __shared__ int   cntL[QT];
    // LDS total ~52 KB -> 3 blocks/CU

    const int tid = threadIdx.x;
    const int L   = tid & 63;
    const int wv  = tid >> 6;
    const int lb  = blockIdx.x;
    const int ch  = lb & 7;                           // XCD-affine chunk
    const int qbase  = (lb >> 3) * QT;
    const int chBase = ch * CHUNK;
    const int nwv = wv * 64;                          // wave's 64-col n window

    if (tid < QT) { cntL[tid] = 0; thrL[tid] = inf_f(); }

    // A fragments in registers, constant indexing only.
    const int am = L & 15, aq = L >> 4;
    half8 afh[2][4], afr[2][4];
    #pragma unroll
    for (int qt = 0; qt < 2; ++qt)
        #pragma unroll
        for (int ks = 0; ks < 4; ++ks) {
            size_t o = (size_t)(qbase + qt * 16 + am) * D_ + ks * 32 + aq * 8;
            afh[qt][ks] = *(const half8*)(Qh + o);
            afr[qt][ks] = *(const half8*)(Qr + o);
        }

    #pragma unroll 1
    for (int it = 0; it < ITERS; ++it) {
        const int nbase = chBase + it * BN;
        floatx4 acc[2][4] = {};

        #pragma unroll
        for (int ks = 0; ks < 4; ++ks) {
            __syncthreads();   // Bh region free (prev mfma reads / filter done)
            // async stage Bh[256][32] for k-window [ks*32, +32): 4 segs/wave,
            // dest = seg base + lane*16 (16 rows x 64 B per seg, contiguous)
            #pragma unroll
            for (int rep = 0; rep < 4; ++rep) {
                int seg = wv * 4 + rep;               // 16-row segment
                int row = seg * 16 + (L >> 2);
                const __half* gsrc =
                    Xh + (size_t)(nbase + row) * D_ + ks * 32 + (L & 3) * 8;
                GLD16(gsrc, Bh + seg * 512);
            }
            if (ks == 0)
                GLD4(tsq + nbase + nwv + L, tsqT + nwv);
            __syncthreads();   // compiler drains vmcnt before barrier
            #pragma unroll
            for (int nt = 0; nt < 4; ++nt) {
                half8 bh = *(const half8*)(Bh + (nwv + nt * 16 + am) * 32 + aq * 8);
                #pragma unroll
                for (int qt = 0; qt < 2; ++qt) {
                    acc[qt][nt] = __builtin_amdgcn_mfma_f32_16x16x32_f16(
                        afh[qt][ks], bh, acc[qt][nt], 0, 0, 0);   // qh . xh
                    acc[qt][nt] = __builtin_amdgcn_mfma_f32_16x16x32_f16(
                        afr[qt][ks], bh, acc[qt][nt], 0, 0, 0);   // qr . xh
                }
            }
        }
        __syncthreads();       // all mfma reads done -> reuse space as scores
        #pragma unroll
        for (int qt = 0; qt < 2; ++qt)
            #pragma unroll
            for (int nt = 0; nt < 4; ++nt)
                #pragma unroll
                for (int rg = 0; rg < 4; ++rg) {
                    int q = qt * 16 + aq * 4 + rg;            // C row = query
                    int n = nwv + nt * 16 + am;               // C col = point
                    sc[q * SCS + n] = acc[qt][nt][rg];
                }
        __syncthreads();

        // Wave-private filter: wave wv owns queries [8wv, 8wv+8), all 256 n.
        #pragma unroll 1
        for (int q8 = 0; q8 < 8; ++q8) {
            const int q = wv * 8 + q8;
            int   cnt_c = cntL[q];
            float thr_c = thrL[q];
            float4 d  = *(const float4*)(sc + q * SCS + 4 * L);
            float4 t4 = *(const float4*)(tsqT + 4 * L);
            float s0 = t4.x - 2.f * d.x, s1 = t4.y - 2.f * d.y;
            float s2 = t4.z - 2.f * d.z, s3 = t4.w - 2.f * d.w;
            bool anyw = (s0 < thr_c) | (s1 < thr_c) | (s2 < thr_c) | (s3 < thr_c);
            if (__ballot(anyw)) {
                #pragma unroll
                for (int j = 0; j < 4; ++j) {
                    float sj = (j == 0) ? s0 : (j == 1) ? s1 : (j == 2) ? s2 : s3;
                    unsigned int ng = (unsigned int)(nbase + 4 * L + j);
                    bool want = sj < thr_c;
                    while (__ballot(want)) {
                        ull wm = __ballot(want);
                        int pos = cnt_c + __popcll(wm & ((1ull << L) - 1ull));
                        if (want && pos < CCAP) {
                            cand[q][pos] = pack_cand(sj, ng);
                            want = false;
                        }
                        int added = (int)__popcll(wm);
                        cnt_c = (cnt_c + added > CCAP) ? CCAP : cnt_c + added;
                        if (__ballot(want)) {     // overflow -> wave compact
                            ull v = (L < cnt_c) ? cand[q][L] : ~0ull;
                            #pragma unroll
                            for (int k = 2; k <= 64; k <<= 1)
                                #pragma unroll
                                for (int jj = k >> 1; jj >= 1; jj >>= 1) {
                                    ull o = __shfl_xor(v, jj);
                                    bool up = ((L & k) == 0);
                                    bool lo = ((L & jj) == 0);
                                    ull mn = u64min(v, o), mx = v ^ o ^ mn;
                                    v = (lo == up) ? mn : mx;
                                }
                            if (L < K_) cand[q][L] = v;
                            cnt_c = K_;
                            thr_c = unpack_score(__shfl(v, K_ - 1));
                            want = want && (sj < thr_c);
                        }
                    }
                }
            }
            cntL[q] = cnt_c;
            thrL[q] = thr_c;
        }
        // next iter's first __syncthreads() orders sc/cand phases
    }

    // final: sort each owned query's buffer, emit sorted approx top-32
    #pragma unroll 1
    for (int q8 = 0; q8 < 8; ++q8) {
        const int q = wv * 8 + q8;
        int m = cntL[q]; if (m > CCAP) m = CCAP;
        ull v = (L < m) ? cand[q][L] : ~0ull;
        #pragma unroll
        for (int k = 2; k <= 64; k <<= 1)
            #pragma unroll
            for (int jj = k >> 1; jj >= 1; jj >>= 1) {
                ull o = __shfl_xor(v, jj);
                bool up = ((L & k) == 0);
                bool lo = ((L & jj) == 0);
                ull mn = u64min(v, o), mx = v ^ o ^ mn;
                v = (lo == up) ? mn : mx;
            }
        if (L < K_)
            candOut[((size_t)(qbase + q) * NCH + ch) * K_ + L] = v;
    }
}

// ---------------------------------------------------- merge + exact rescore -
__global__ void merge_rescore(const ull* __restrict__ candIn,
                              const float* __restrict__ Qm,
                              const float* __restrict__ X,
                              const float* __restrict__ tsq,
                              const float* __restrict__ Ytr,
                              float* __restrict__ out)
{
    int L  = threadIdx.x & 63;
    int q  = blockIdx.x * 4 + (threadIdx.x >> 6);   // one wave per query
    const ull* p = candIn + (size_t)q * (NCH * K_); // 256 approx candidates
    ull r0 = p[L], r1 = p[L + 64], r2 = p[L + 128], r3 = p[L + 192];

    // approx top-MKEEP; lane i captures the i-th best
    ull sel = ~0ull;
    #pragma unroll 1
    for (int i = 0; i < MKEEP; ++i) {
        ull g = u64min(u64min(r0, r1), u64min(r2, r3));
        g = u64min(g, __shfl_xor(g, 32)); g = u64min(g, __shfl_xor(g, 16));
        g = u64min(g, __shfl_xor(g, 8));  g = u64min(g, __shfl_xor(g, 4));
        g = u64min(g, __shfl_xor(g, 2));  g = u64min(g, __shfl_xor(g, 1));
        if (L == i) sel = g;
        bool has = (r0 == g) | (r1 == g) | (r2 == g) | (r3 == g);
        int fl = __ffsll(__ballot(has)) - 1;
        if (L == fl) {
            if (r0 == g) r0 = ~0ull; else if (r1 == g) r1 = ~0ull;
            else if (r2 == g) r2 = ~0ull; else r3 = ~0ull;
        }
    }

    // exact fp32 rescore of the MKEEP candidates (wave-cooperative dot)
    float2 qv = *(const float2*)(Qm + (size_t)q * D_ + 2 * L);
    ull key = ~0ull;
    #pragma unroll 1
    for (int c = 0; c < MKEEP; ++c) {
        ull s = __shfl(sel, c);
        unsigned int n = (unsigned int)(s & 0xffffffffu);
        float2 xv = *(const float2*)(X + (size_t)n * D_ + 2 * L);
        float pd = qv.x * xv.x + qv.y * xv.y;
        pd += __shfl_xor(pd, 32); pd += __shfl_xor(pd, 16);
        pd += __shfl_xor(pd, 8);  pd += __shfl_xor(pd, 4);
        pd += __shfl_xor(pd, 2);  pd += __shfl_xor(pd, 1);
        float scv = tsq[n] - 2.f * pd;
        if (L == c) key = pack_cand(scv, n);
    }

    // exact top-32 of MKEEP, mean of y
    ull kv = key;
    bool kept = false;
    #pragma unroll 1
    for (int i = 0; i < K_; ++i) {
        ull g = kv;
        g = u64min(g, __shfl_xor(g, 32)); g = u64min(g, __shfl_xor(g, 16));
        g = u64min(g, __shfl_xor(g, 8));  g = u64min(g, __shfl_xor(g, 4));
        g = u64min(g, __shfl_xor(g, 2));  g = u64min(g, __shfl_xor(g, 1));
        int fl = __ffsll(__ballot(kv == g)) - 1;
        if (L == fl) { kv = ~0ull; kept = true; }
    }
    float ys = kept ? Ytr[(unsigned int)(key & 0xffffffffu)] : 0.f;
    ys += __shfl_xor(ys, 32); ys += __shfl_xor(ys, 16); ys += __shfl_xor(ys, 8);
    ys += __shfl_xor(ys, 4);  ys += __shfl_xor(ys, 2);  ys += __shfl_xor(ys, 1);
    if (L == 0) out[q] = ys * (1.f / K_);
}

// ------------------------------------------------------------- launch -------
extern "C" void kernel_launch(void* const* d_in, const int* in_sizes, int n_in,
                              void* d_out, int out_size, void* d_ws, size_t ws_size,
                              hipStream_t stream)
{
    const float* Qm  = (const float*)d_in[0];   // [4096,128]
    const float* X   = (const float*)d_in[1];   // [100000,128]
    const float* Ytr = (const float*)d_in[2];   // [100000]
    float* out = (float*)d_out;                 // [4096]

    char* w = (char*)d_ws;
    __half* Xh = (__half*)w;                         w += (size_t)NPAD * D_ * 2;  // 25.7 MB
    __half* Qh = (__half*)w;                         w += (size_t)Q_ * D_ * 2;    // 1 MB
    __half* Qr = (__half*)w;                         w += (size_t)Q_ * D_ * 2;    // 1 MB
    float*  ts = (float*)w;                          w += (size_t)NPAD * 4;       // 0.4 MB
    ull*    cd = (ull*)w;                            // 8.4 MB  (total ~36.5 MB)

    prep_x<<<NPAD / 4, 256, 0, stream>>>(X, Xh, ts);
    prep_q<<<Q_ / 4, 256, 0, stream>>>(Qm, Qh, Qr);
    knn_main<<<(Q_ / QT) * NCH, 256, 0, stream>>>(Qh, Qr, Xh, ts, cd);
    merge_rescore<<<Q_ / 4, 256, 0, stream>>>(cd, Qm, X, ts, Ytr, out);
}

// Round 4
// 1056.929 us; speedup vs baseline: 191.1653x; 1.1032x over previous
//
#include <hip/hip_runtime.h>
#include <hip/hip_fp16.h>
#include <cstdint>
#include <cstddef>

// KNN regressor, MFMA edition v4 — barrier-minimal.
//   score[n] = tsq[n] - 2*dot(q, x_n)
// dot via 2-pass fp16 split: q = qh + qr, x ~ xh;  dot ≈ qh·xh + qr·xh.
// Per-chunk approx top-32 -> merge -> approx top-40 -> EXACT fp32 rescore
// -> exact top-32 -> mean(y).
//
// v4 key change: NO LDS staging of B (no cross-wave reuse existed — each wave
// reads only its own 64-column window). B fragments are loaded directly
// global->VGPR from a fragment-swizzled Xs layout (1 KB contiguous per wave
// fragment => one coalesced global_load_dwordx4 per fragment, L2-resident via
// XCD-affine chunk mapping). Barriers: 10/iter -> 2/iter (score transpose).
//
// MFMA 16x16x32 f16 layouts (HW-verified, learn_hip m89/m91/m120):
//   A[m][k]: m = lane&15, k = (lane>>4)*8 + j
//   B[k][n]: n = lane&15, k = (lane>>4)*8 + j
//   C[m][n]: n(col) = lane&15, m(row) = (lane>>4)*4 + reg
//
// Xs swizzle: segment s = (n>>4)*4 + ks holds, at half8-index s*64 + L,
// the 8 halves Xh[row=(n&~15)+(L&15)][k=ks*32+(L>>4)*8 .. +8].

constexpr int Q_  = 4096;
constexpr int N_  = 100000;
constexpr int D_  = 128;
constexpr int K_  = 32;

constexpr int QT    = 32;            // queries per block
constexpr int BN    = 256;           // n per iteration
constexpr int NCH   = 8;             // chunks (ch = blockIdx.x & 7, XCD-affine)
constexpr int CHUNK = 12544;         // 49*256
constexpr int ITERS = CHUNK / BN;    // 49
constexpr int NPAD  = NCH * CHUNK;   // 100352
constexpr int CCAP  = 64;            // per-query candidate buffer
constexpr int MKEEP = 40;            // approx top kept for exact rescore
constexpr int SCS   = 260;           // sc row stride (floats): free 2-way banks

typedef __attribute__((ext_vector_type(8))) _Float16 half8;
typedef __attribute__((ext_vector_type(4))) float    floatx4;
typedef unsigned long long ull;

#define DEV __device__ __forceinline__

DEV ull pack_cand(float score, unsigned int n) {
    unsigned int s = __float_as_uint(score);
    s = (s & 0x80000000u) ? ~s : (s | 0x80000000u);   // monotone u32 key
    return ((ull)s << 32) | (ull)n;
}
DEV float unpack_score(ull k) {
    unsigned int s = (unsigned int)(k >> 32);
    s = (s & 0x80000000u) ? (s ^ 0x80000000u) : ~s;
    return __uint_as_float(s);
}
DEV ull u64min(ull a, ull b) { return a < b ? a : b; }
DEV float inf_f() { return __int_as_float(0x7f800000); }

// ---------------------------------------------------------------- prep ------
// One wave per 16-row tile: writes the 4 swizzled 1 KB segments + tsq rows.
__global__ void prep_xs(const float* __restrict__ X, __half* __restrict__ Xs,
                        float* __restrict__ tsq) {
    int L   = threadIdx.x & 63;
    int t16 = blockIdx.x * 4 + (threadIdx.x >> 6);   // tile; t16 < NPAD/16
    int am = L & 15, aq = L >> 4;
    int r = t16 * 16 + am;
    float ssq = 0.f;
    #pragma unroll
    for (int ks = 0; ks < 4; ++ks) {
        int c = ks * 32 + aq * 8;
        float4 a = {0.f,0.f,0.f,0.f}, b = {0.f,0.f,0.f,0.f};
        if (r < N_) {
            a = *(const float4*)(X + (size_t)r * D_ + c);
            b = *(const float4*)(X + (size_t)r * D_ + c + 4);
        }
        half8 h;
        h[0] = (_Float16)a.x; h[1] = (_Float16)a.y;
        h[2] = (_Float16)a.z; h[3] = (_Float16)a.w;
        h[4] = (_Float16)b.x; h[5] = (_Float16)b.y;
        h[6] = (_Float16)b.z; h[7] = (_Float16)b.w;
        *(half8*)(Xs + ((size_t)(t16 * 4 + ks)) * 512 + L * 8) = h;
        ssq += a.x*a.x + a.y*a.y + a.z*a.z + a.w*a.w
             + b.x*b.x + b.y*b.y + b.z*b.z + b.w*b.w;
    }
    // reduce across the 4 aq groups (same am): lanes differ in bits 4,5
    ssq += __shfl_xor(ssq, 16);
    ssq += __shfl_xor(ssq, 32);
    if (aq == 0) tsq[r] = (r < N_) ? ssq : inf_f();
}

__global__ void prep_q(const float* __restrict__ Qm, __half* __restrict__ Qh,
                       __half* __restrict__ Qr) {
    int L = threadIdx.x & 63;
    int r = blockIdx.x * 4 + (threadIdx.x >> 6);     // r < 4096 by grid
    float2 x = *(const float2*)(Qm + (size_t)r * D_ + 2 * L);
    __half h0 = __float2half(x.x), h1 = __float2half(x.y);
    size_t o = (size_t)r * D_ + 2 * L;
    Qh[o] = h0; Qh[o + 1] = h1;
    Qr[o]     = __float2half(x.x - __half2float(h0));
    Qr[o + 1] = __float2half(x.y - __half2float(h1));
}

// ------------------------------------------------------------- main ---------
__global__ __launch_bounds__(256, 3) void knn_main(
    const __half* __restrict__ Qh, const __half* __restrict__ Qr,
    const __half* __restrict__ Xs, const float* __restrict__ tsq,
    ull* __restrict__ candOut)
{
    __shared__ __align__(16) float sc[QT * SCS];      // 33280 B score transpose
    __shared__ ull   cand[QT][CCAP];                  // 16 KB (score|n)
    __shared__ float thrL[QT];
    __shared__ int   cntL[QT];
    // LDS ~50 KB -> 3 blocks/CU

    const int tid = threadIdx.x;
    const int L   = tid & 63;
    const int wv  = tid >> 6;
    const int lb  = blockIdx.x;
    const int ch  = lb & 7;                           // XCD-affine chunk
    const int qbase  = (lb >> 3) * QT;
    const int chBase = ch * CHUNK;
    const int nwv = wv * 64;                          // wave's 64-col n window

    if (tid < QT) { cntL[tid] = 0; thrL[tid] = inf_f(); }

    // A fragments in registers, constant indexing only.
    const int am = L & 15, aq = L >> 4;
    half8 afh[2][4], afr[2][4];
    #pragma unroll
    for (int qt = 0; qt < 2; ++qt)
        #pragma unroll
        for (int ks = 0; ks < 4; ++ks) {
            size_t o = (size_t)(qbase + qt * 16 + am) * D_ + ks * 32 + aq * 8;
            afh[qt][ks] = *(const half8*)(Qh + o);
            afr[qt][ks] = *(const half8*)(Qr + o);
        }

    const half8* sp = (const half8*)Xs;               // half8-granular view

    #pragma unroll 1
    for (int it = 0; it < ITERS; ++it) {
        const int nbase = chBase + it * BN;
        const size_t segb = (size_t)((nbase + nwv) >> 4) * 4;  // seg of (nt=0,ks=0)
        floatx4 acc[2][4] = {};

        // ks-pipelined MFMA: B frags direct global->VGPR (L2-resident, no LDS)
        half8 bc[4], bn[4];
        #pragma unroll
        for (int nt = 0; nt < 4; ++nt)
            bc[nt] = sp[(segb + nt * 4 + 0) * 64 + L];
        #pragma unroll
        for (int ks = 0; ks < 4; ++ks) {
            if (ks < 3) {
                #pragma unroll
                for (int nt = 0; nt < 4; ++nt)
                    bn[nt] = sp[(segb + nt * 4 + ks + 1) * 64 + L];
            }
            #pragma unroll
            for (int nt = 0; nt < 4; ++nt)
                #pragma unroll
                for (int qt = 0; qt < 2; ++qt) {
                    acc[qt][nt] = __builtin_amdgcn_mfma_f32_16x16x32_f16(
                        afh[qt][ks], bc[nt], acc[qt][nt], 0, 0, 0);  // qh.xh
                    acc[qt][nt] = __builtin_amdgcn_mfma_f32_16x16x32_f16(
                        afr[qt][ks], bc[nt], acc[qt][nt], 0, 0, 0);  // qr.xh
                }
            if (ks < 3) {
                #pragma unroll
                for (int nt = 0; nt < 4; ++nt) bc[nt] = bn[nt];
            }
        }

        __syncthreads();       // prev iter's filter done reading sc
        #pragma unroll
        for (int qt = 0; qt < 2; ++qt)
            #pragma unroll
            for (int nt = 0; nt < 4; ++nt)
                #pragma unroll
                for (int rg = 0; rg < 4; ++rg) {
                    int q = qt * 16 + aq * 4 + rg;            // C row = query
                    int n = nwv + nt * 16 + am;               // C col = point
                    sc[q * SCS + n] = acc[qt][nt][rg];
                }
        __syncthreads();

        // Wave-private filter: wave wv owns queries [8wv, 8wv+8), all 256 n.
        #pragma unroll 1
        for (int q8 = 0; q8 < 8; ++q8) {
            const int q = wv * 8 + q8;
            int   cnt_c = cntL[q];
            float thr_c = thrL[q];
            float4 d  = *(const float4*)(sc + q * SCS + 4 * L);
            float4 t4 = *(const float4*)(tsq + nbase + 4 * L); // global, L2-hit
            float s0 = t4.x - 2.f * d.x, s1 = t4.y - 2.f * d.y;
            float s2 = t4.z - 2.f * d.z, s3 = t4.w - 2.f * d.w;
            bool anyw = (s0 < thr_c) | (s1 < thr_c) | (s2 < thr_c) | (s3 < thr_c);
            if (__ballot(anyw)) {
                #pragma unroll
                for (int j = 0; j < 4; ++j) {
                    float sj = (j == 0) ? s0 : (j == 1) ? s1 : (j == 2) ? s2 : s3;
                    unsigned int ng = (unsigned int)(nbase + 4 * L + j);
                    bool want = sj < thr_c;
                    while (__ballot(want)) {
                        ull wm = __ballot(want);
                        int pos = cnt_c + __popcll(wm & ((1ull << L) - 1ull));
                        if (want && pos < CCAP) {
                            cand[q][pos] = pack_cand(sj, ng);
                            want = false;
                        }
                        int added = (int)__popcll(wm);
                        cnt_c = (cnt_c + added > CCAP) ? CCAP : cnt_c + added;
                        if (__ballot(want)) {     // overflow -> wave compact
                            ull v = (L < cnt_c) ? cand[q][L] : ~0ull;
                            #pragma unroll
                            for (int k = 2; k <= 64; k <<= 1)
                                #pragma unroll
                                for (int jj = k >> 1; jj >= 1; jj >>= 1) {
                                    ull o = __shfl_xor(v, jj);
                                    bool up = ((L & k) == 0);
                                    bool lo = ((L & jj) == 0);
                                    ull mn = u64min(v, o), mx = v ^ o ^ mn;
                                    v = (lo == up) ? mn : mx;
                                }
                            if (L < K_) cand[q][L] = v;
                            cnt_c = K_;
                            thr_c = unpack_score(__shfl(v, K_ - 1));
                            want = want && (sj < thr_c);
                        }
                    }
                }
            }
            cntL[q] = cnt_c;
            thrL[q] = thr_c;
        }
        // next iter's first __syncthreads() orders sc/cand phases
    }

    // final: sort each owned query's buffer, emit sorted approx top-32
    #pragma unroll 1
    for (int q8 = 0; q8 < 8; ++q8) {
        const int q = wv * 8 + q8;
        int m = cntL[q]; if (m > CCAP) m = CCAP;
        ull v = (L < m) ? cand[q][L] : ~0ull;
        #pragma unroll
        for (int k = 2; k <= 64; k <<= 1)
            #pragma unroll
            for (int jj = k >> 1; jj >= 1; jj >>= 1) {
                ull o = __shfl_xor(v, jj);
                bool up = ((L & k) == 0);
                bool lo = ((L & jj) == 0);
                ull mn = u64min(v, o), mx = v ^ o ^ mn;
                v = (lo == up) ? mn : mx;
            }
        if (L < K_)
            candOut[((size_t)(qbase + q) * NCH + ch) * K_ + L] = v;
    }
}

// ---------------------------------------------------- merge + exact rescore -
__global__ void merge_rescore(const ull* __restrict__ candIn,
                              const float* __restrict__ Qm,
                              const float* __restrict__ X,
                              const float* __restrict__ tsq,
                              const float* __restrict__ Ytr,
                              float* __restrict__ out)
{
    int L  = threadIdx.x & 63;
    int q  = blockIdx.x * 4 + (threadIdx.x >> 6);   // one wave per query
    const ull* p = candIn + (size_t)q * (NCH * K_); // 256 approx candidates
    ull r0 = p[L], r1 = p[L + 64], r2 = p[L + 128], r3 = p[L + 192];

    // approx top-MKEEP; lane i captures the i-th best
    ull sel = ~0ull;
    #pragma unroll 1
    for (int i = 0; i < MKEEP; ++i) {
        ull g = u64min(u64min(r0, r1), u64min(r2, r3));
        g = u64min(g, __shfl_xor(g, 32)); g = u64min(g, __shfl_xor(g, 16));
        g = u64min(g, __shfl_xor(g, 8));  g = u64min(g, __shfl_xor(g, 4));
        g = u64min(g, __shfl_xor(g, 2));  g = u64min(g, __shfl_xor(g, 1));
        if (L == i) sel = g;
        bool has = (r0 == g) | (r1 == g) | (r2 == g) | (r3 == g);
        int fl = __ffsll(__ballot(has)) - 1;
        if (L == fl) {
            if (r0 == g) r0 = ~0ull; else if (r1 == g) r1 = ~0ull;
            else if (r2 == g) r2 = ~0ull; else r3 = ~0ull;
        }
    }

    // exact fp32 rescore of the MKEEP candidates (wave-cooperative dot)
    float2 qv = *(const float2*)(Qm + (size_t)q * D_ + 2 * L);
    ull key = ~0ull;
    #pragma unroll 1
    for (int c = 0; c < MKEEP; ++c) {
        ull s = __shfl(sel, c);
        unsigned int n = (unsigned int)(s & 0xffffffffu);
        float2 xv = *(const float2*)(X + (size_t)n * D_ + 2 * L);
        float pd = qv.x * xv.x + qv.y * xv.y;
        pd += __shfl_xor(pd, 32); pd += __shfl_xor(pd, 16);
        pd += __shfl_xor(pd, 8);  pd += __shfl_xor(pd, 4);
        pd += __shfl_xor(pd, 2);  pd += __shfl_xor(pd, 1);
        float scv = tsq[n] - 2.f * pd;
        if (L == c) key = pack_cand(scv, n);
    }

    // exact top-32 of MKEEP, mean of y
    ull kv = key;
    bool kept = false;
    #pragma unroll 1
    for (int i = 0; i < K_; ++i) {
        ull g = kv;
        g = u64min(g, __shfl_xor(g, 32)); g = u64min(g, __shfl_xor(g, 16));
        g = u64min(g, __shfl_xor(g, 8));  g = u64min(g, __shfl_xor(g, 4));
        g = u64min(g, __shfl_xor(g, 2));  g = u64min(g, __shfl_xor(g, 1));
        int fl = __ffsll(__ballot(kv == g)) - 1;
        if (L == fl) { kv = ~0ull; kept = true; }
    }
    float ys = kept ? Ytr[(unsigned int)(key & 0xffffffffu)] : 0.f;
    ys += __shfl_xor(ys, 32); ys += __shfl_xor(ys, 16); ys += __shfl_xor(ys, 8);
    ys += __shfl_xor(ys, 4);  ys += __shfl_xor(ys, 2);  ys += __shfl_xor(ys, 1);
    if (L == 0) out[q] = ys * (1.f / K_);
}

// ------------------------------------------------------------- launch -------
extern "C" void kernel_launch(void* const* d_in, const int* in_sizes, int n_in,
                              void* d_out, int out_size, void* d_ws, size_t ws_size,
                              hipStream_t stream)
{
    const float* Qm  = (const float*)d_in[0];   // [4096,128]
    const float* X   = (const float*)d_in[1];   // [100000,128]
    const float* Ytr = (const float*)d_in[2];   // [100000]
    float* out = (float*)d_out;                 // [4096]

    char* w = (char*)d_ws;
    __half* Xs = (__half*)w;                         w += (size_t)NPAD * D_ * 2;  // 25.7 MB
    __half* Qh = (__half*)w;                         w += (size_t)Q_ * D_ * 2;    // 1 MB
    __half* Qr = (__half*)w;                         w += (size_t)Q_ * D_ * 2;    // 1 MB
    float*  ts = (float*)w;                          w += (size_t)NPAD * 4;       // 0.4 MB
    ull*    cd = (ull*)w;                            // 8.4 MB  (total ~36.5 MB)

    prep_xs<<<NPAD / 64, 256, 0, stream>>>(X, Xs, ts);
    prep_q<<<Q_ / 4, 256, 0, stream>>>(Qm, Qh, Qr);
    knn_main<<<(Q_ / QT) * NCH, 256, 0, stream>>>(Qh, Qr, Xs, ts, cd);
    merge_rescore<<<Q_ / 4, 256, 0, stream>>>(cd, Qm, X, ts, Ytr, out);
}